// Round 1
// baseline (590.391 us; speedup 1.0000x reference)
//
#include <hip/hip_runtime.h>
#include <hip/hip_bf16.h>

// Disable FP contraction everywhere: IoU / threshold comparisons must match
// numpy/jax f32 op-by-op rounding (an fma in "a+b - iw*ih" would flip keeps).
#pragma clang fp contract(off)

#define NUM_CLASSES 100
#define B_DIM 8
#define N_DIM 32768
#define TOPK_K 1024
#define ROW_F 105
#define CONF_THRE_F 0.001f
#define NMS_THRE_F 0.65f
#define OFFSET_F 241.0f   // MAX_DIM + 1

// ---------------------------------------------------------------------------
// Kernel 1: decode + class max/argmax + ordered sort key
// Each wave processes rows with the same (row*105) mod 4 so float4 loads are
// 16B-aligned; template<S> keeps every register index compile-time constant.
// key = (ordered_score(32b) << 15) | (32767 - n)  -- unique per batch.
// ---------------------------------------------------------------------------
template <int S>
__device__ __forceinline__ void process_row(const float* pal,
                                            float& cx, float& cy, float& ww, float& hh,
                                            float& obj, float& cmax, int& cidx) {
    const float4* p4 = reinterpret_cast<const float4*>(pal);
    cmax = -1.0f; cidx = 0;
    cx = 0.f; cy = 0.f; ww = 0.f; hh = 0.f; obj = 0.f;
#pragma unroll
    for (int jj = 0; jj < 27; ++jj) {
        float4 v = p4[jj];
#pragma unroll
        for (int e = 0; e < 4; ++e) {
            const int pos = jj * 4 + e;
            float f = (e == 0) ? v.x : (e == 1) ? v.y : (e == 2) ? v.z : v.w;
            if (pos == S + 0) cx = f;
            else if (pos == S + 1) cy = f;
            else if (pos == S + 2) ww = f;
            else if (pos == S + 3) hh = f;
            else if (pos == S + 4) obj = f;
            else if (pos >= S + 5 && pos <= S + 104) {
                const int c = pos - (S + 5);
                if (f > cmax) { cmax = f; cidx = c; }
            }
        }
    }
}

__global__ __launch_bounds__(256) void decode_kernel(const float* __restrict__ pred,
                                                     unsigned long long* __restrict__ keys,
                                                     unsigned char* __restrict__ labels) {
    const int wv   = threadIdx.x >> 6;   // 0..3, == (105*r) % 4 for this wave's rows
    const int lane = threadIdx.x & 63;
    const int base = blockIdx.x << 8;    // 256 rows per block
    const int r    = base + wv + (lane << 2);

    const float* pal = pred + ((size_t)r * ROW_F - (size_t)wv); // 16B aligned

    float cx, cy, ww, hh, obj, cmax; int cidx;
    switch (wv) {
        case 0: process_row<0>(pal, cx, cy, ww, hh, obj, cmax, cidx); break;
        case 1: process_row<1>(pal, cx, cy, ww, hh, obj, cmax, cidx); break;
        case 2: process_row<2>(pal, cx, cy, ww, hh, obj, cmax, cidx); break;
        default: process_row<3>(pal, cx, cy, ww, hh, obj, cmax, cidx); break;
    }

    float score = obj * cmax;                       // same op order as reference
    bool valid  = (score * cmax) >= CONF_THRE_F;
    float m     = valid ? score : -1.0f;

    unsigned int u  = __float_as_uint(m);
    unsigned int ou = (u & 0x80000000u) ? ~u : (u | 0x80000000u); // order-preserving
    int n = r & (N_DIM - 1);
    unsigned long long key = ((unsigned long long)ou << 15) | (unsigned)(n ^ (N_DIM - 1));

    keys[r]   = key;
    labels[r] = (unsigned char)cidx;
}

// ---------------------------------------------------------------------------
// Kernel 2: per-batch exact top-1024 (MSB radix select on 47-bit unique keys),
// then LDS bitonic sort; write keys sorted DESCENDING (== lax.top_k order).
// ---------------------------------------------------------------------------
__global__ __launch_bounds__(256) void select_kernel(const unsigned long long* __restrict__ keys,
                                                     unsigned long long* __restrict__ topkeys) {
    const int b   = blockIdx.x;
    const int tid = threadIdx.x;
    const unsigned long long* K = keys + (size_t)b * N_DIM;

    __shared__ unsigned int hist[256];
    __shared__ unsigned long long prefix_s;
    __shared__ unsigned int remaining_s;
    __shared__ unsigned int cnt_s;
    __shared__ unsigned long long sel[TOPK_K];

    if (tid == 0) { prefix_s = 0ull; remaining_s = TOPK_K; cnt_s = 0u; }
    __syncthreads();

    for (int level = 0; level < 6; ++level) {
        const int shift = 40 - 8 * level;
        hist[tid] = 0u;
        __syncthreads();
        unsigned long long pref = prefix_s;
        for (int n = tid; n < N_DIM; n += 256) {
            unsigned long long k = K[n];
            if ((k >> (shift + 8)) == pref)
                atomicAdd(&hist[(unsigned)(k >> shift) & 255u], 1u);
        }
        __syncthreads();
        if (tid == 0) {
            unsigned int rem = remaining_s;
            unsigned int cum = 0;
            for (int d = 255; d >= 0; --d) {
                unsigned int c = hist[d];
                if (cum + c >= rem) {
                    prefix_s = (prefix_s << 8) | (unsigned long long)d;
                    remaining_s = rem - cum;   // still needed among digit==d
                    break;
                }
                cum += c;
            }
        }
        __syncthreads();
    }

    const unsigned long long T = prefix_s;  // exact 1024th-largest key
    for (int n = tid; n < N_DIM; n += 256) {
        unsigned long long k = K[n];
        if (k >= T) {
            unsigned p = atomicAdd(&cnt_s, 1u);
            sel[p] = k;   // exactly 1024 by uniqueness
        }
    }
    __syncthreads();

    // bitonic sort ascending
    for (int kk = 2; kk <= TOPK_K; kk <<= 1) {
        for (int j = kk >> 1; j > 0; j >>= 1) {
            for (int t = tid; t < TOPK_K; t += 256) {
                int ixj = t ^ j;
                if (ixj > t) {
                    unsigned long long a = sel[t], c2 = sel[ixj];
                    bool up = ((t & kk) == 0);
                    if ((a > c2) == up) { sel[t] = c2; sel[ixj] = a; }
                }
            }
            __syncthreads();
        }
    }

    for (int t = tid; t < TOPK_K; t += 256)
        topkeys[(size_t)b * TOPK_K + t] = sel[(TOPK_K - 1) - t];  // descending
}

// ---------------------------------------------------------------------------
// Kernel 3: gather boxes, greedy NMS (chunked: wave-serial within 64-chunk via
// shfl/ballot, then block-parallel suppression of later boxes), write output.
// ---------------------------------------------------------------------------
__global__ __launch_bounds__(1024) void nms_kernel(const float* __restrict__ pred,
                                                   const unsigned char* __restrict__ labels,
                                                   const unsigned long long* __restrict__ topkeys,
                                                   float* __restrict__ out) {
    const int b = blockIdx.x;
    const int j = threadIdx.x;

    __shared__ float sx1[TOPK_K], sy1[TOPK_K], sx2[TOPK_K], sy2[TOPK_K], sarea[TOPK_K];
    __shared__ unsigned char svalid[TOPK_K];
    __shared__ unsigned char skeep[TOPK_K];
    __shared__ unsigned long long keepmask_s;

    unsigned long long key = topkeys[(size_t)b * TOPK_K + j];
    int n = (N_DIM - 1) - (int)(key & (unsigned long long)(N_DIM - 1));
    unsigned int ou = (unsigned int)(key >> 15);
    unsigned int ob = (ou & 0x80000000u) ? (ou & 0x7FFFFFFFu) : ~ou;
    float score = __uint_as_float(ob);         // masked score (== top_vals)
    bool validk = (score >= 0.0f);
    int lab = (int)labels[(size_t)b * N_DIM + n];

    const float* row = pred + ((size_t)b * N_DIM + n) * ROW_F;
    float cx = row[0], cy = row[1], w = row[2], h = row[3];
    float x1 = cx - w * 0.5f, y1 = cy - h * 0.5f;
    float x2 = w + x1,        y2 = h + y1;          // reference: xy2 = wh + xy1
    float off = (float)lab * OFFSET_F;
    float nx1 = x1 + off, ny1 = y1 + off, nx2 = x2 + off, ny2 = y2 + off;
    float area = (nx2 - nx1) * (ny2 - ny1);         // area from OFFSET boxes (ref)

    sx1[j] = nx1; sy1[j] = ny1; sx2[j] = nx2; sy2[j] = ny2; sarea[j] = area;
    svalid[j] = validk ? 1 : 0;
    skeep[j] = 0;
    __syncthreads();

    for (int c = 0; c < TOPK_K / 64; ++c) {
        if (j < 64) {
            const int i0 = c * 64 + j;
            float bx1 = sx1[i0], by1 = sy1[i0], bx2 = sx2[i0], by2 = sy2[i0], ba = sarea[i0];
            unsigned long long vm = __ballot(svalid[i0] != 0);
            unsigned long long suppmask = 0ull, keepm = 0ull;
            for (int i = 0; i < 64; ++i) {
                float ax1 = __shfl(bx1, i), ay1 = __shfl(by1, i);
                float ax2 = __shfl(bx2, i), ay2 = __shfl(by2, i);
                float aa  = __shfl(ba, i);
                float ix1 = fmaxf(ax1, bx1), iy1 = fmaxf(ay1, by1);
                float ix2 = fminf(ax2, bx2), iy2 = fminf(ay2, by2);
                float iw = fmaxf(ix2 - ix1, 0.0f), ih = fmaxf(iy2 - iy1, 0.0f);
                float inter = iw * ih;
                float iou = inter / (aa + ba - inter + 1e-12f);
                unsigned long long bits = __ballot(iou > NMS_THRE_F);
                bool can = ((vm >> i) & 1ull) && !((suppmask >> i) & 1ull);
                if (can) { keepm |= (1ull << i); suppmask |= bits; }
            }
            skeep[i0] = (unsigned char)((keepm >> j) & 1ull);
            if ((suppmask >> j) & 1ull) svalid[i0] = 0;
            if (j == 0) keepmask_s = keepm;
        }
        __syncthreads();
        // suppress later boxes with this chunk's keepers
        if (j >= (c + 1) * 64 && svalid[j]) {
            unsigned long long m = keepmask_s;
            while (m) {
                int i = __builtin_ctzll(m); m &= m - 1ull;
                int ig = c * 64 + i;
                float ax1 = sx1[ig], ay1 = sy1[ig], ax2 = sx2[ig], ay2 = sy2[ig], aa = sarea[ig];
                float ix1 = fmaxf(ax1, nx1), iy1 = fmaxf(ay1, ny1);
                float ix2 = fminf(ax2, nx2), iy2 = fminf(ay2, ny2);
                float iw = fmaxf(ix2 - ix1, 0.0f), ih = fmaxf(iy2 - iy1, 0.0f);
                float inter = iw * ih;
                float iou = inter / (aa + area - inter + 1e-12f);
                if (iou > NMS_THRE_F) { svalid[j] = 0; break; }
            }
        }
        __syncthreads();
    }

    float keepf = skeep[j] ? 1.0f : 0.0f;
    float* o = out + ((size_t)b * TOPK_K + j) * 6;
    o[0] = x1 * keepf;
    o[1] = y1 * keepf;
    o[2] = x2 * keepf;
    o[3] = y2 * keepf;
    o[4] = score * keepf;
    o[5] = (float)lab * keepf;
}

// ---------------------------------------------------------------------------
extern "C" void kernel_launch(void* const* d_in, const int* in_sizes, int n_in,
                              void* d_out, int out_size, void* d_ws, size_t ws_size,
                              hipStream_t stream) {
    const float* pred = (const float*)d_in[0];
    float* out = (float*)d_out;

    // workspace layout (~2.63 MB total)
    unsigned long long* keys    = (unsigned long long*)d_ws;                          // 2 MB
    unsigned char*      labels  = (unsigned char*)((char*)d_ws + 2u * 1024 * 1024);   // 256 KB
    unsigned long long* topkeys = (unsigned long long*)((char*)d_ws + 2u * 1024 * 1024 + 512u * 1024); // 64 KB

    decode_kernel<<<(B_DIM * N_DIM) / 256, 256, 0, stream>>>(pred, keys, labels);
    select_kernel<<<B_DIM, 256, 0, stream>>>(keys, topkeys);
    nms_kernel<<<B_DIM, 1024, 0, stream>>>(pred, labels, topkeys, out);
}

// Round 2
// 353.135 us; speedup vs baseline: 1.6719x; 1.6719x over previous
//
#include <hip/hip_runtime.h>
#include <hip/hip_bf16.h>

// Disable FP contraction everywhere: IoU / threshold comparisons must match
// numpy/jax f32 op-by-op rounding (an fma in "a+b - iw*ih" would flip keeps).
#pragma clang fp contract(off)

#define NUM_CLASSES 100
#define B_DIM 8
#define N_DIM 32768
#define TOPK_K 1024
#define ROW_F 105
#define CONF_THRE_F 0.001f
#define NMS_THRE_F 0.65f
#define OFFSET_F 241.0f   // MAX_DIM + 1
#define HBINS 4096        // top-12-bits-of-key histogram

// ---------------------------------------------------------------------------
// Kernel 1: decode + class max/argmax + ordered sort key + 12-bit histogram
// ---------------------------------------------------------------------------
template <int S>
__device__ __forceinline__ void process_row(const float* pal,
                                            float& cx, float& cy, float& ww, float& hh,
                                            float& obj, float& cmax, int& cidx) {
    const float4* p4 = reinterpret_cast<const float4*>(pal);
    cmax = -1.0f; cidx = 0;
    cx = 0.f; cy = 0.f; ww = 0.f; hh = 0.f; obj = 0.f;
#pragma unroll
    for (int jj = 0; jj < 27; ++jj) {
        float4 v = p4[jj];
#pragma unroll
        for (int e = 0; e < 4; ++e) {
            const int pos = jj * 4 + e;
            float f = (e == 0) ? v.x : (e == 1) ? v.y : (e == 2) ? v.z : v.w;
            if (pos == S + 0) cx = f;
            else if (pos == S + 1) cy = f;
            else if (pos == S + 2) ww = f;
            else if (pos == S + 3) hh = f;
            else if (pos == S + 4) obj = f;
            else if (pos >= S + 5 && pos <= S + 104) {
                const int c = pos - (S + 5);
                if (f > cmax) { cmax = f; cidx = c; }
            }
        }
    }
}

__global__ __launch_bounds__(256) void decode_kernel(const float* __restrict__ pred,
                                                     unsigned long long* __restrict__ keys,
                                                     unsigned char* __restrict__ labels,
                                                     unsigned int* __restrict__ hist) {
    const int wv   = threadIdx.x >> 6;   // 0..3, == (105*r) % 4 for this wave's rows
    const int lane = threadIdx.x & 63;
    const int base = blockIdx.x << 8;    // 256 rows per block
    const int r    = base + wv + (lane << 2);

    const float* pal = pred + ((size_t)r * ROW_F - (size_t)wv); // 16B aligned

    float cx, cy, ww, hh, obj, cmax; int cidx;
    switch (wv) {
        case 0: process_row<0>(pal, cx, cy, ww, hh, obj, cmax, cidx); break;
        case 1: process_row<1>(pal, cx, cy, ww, hh, obj, cmax, cidx); break;
        case 2: process_row<2>(pal, cx, cy, ww, hh, obj, cmax, cidx); break;
        default: process_row<3>(pal, cx, cy, ww, hh, obj, cmax, cidx); break;
    }

    float score = obj * cmax;                       // same op order as reference
    bool valid  = (score * cmax) >= CONF_THRE_F;
    float m     = valid ? score : -1.0f;

    unsigned int u  = __float_as_uint(m);
    unsigned int ou = (u & 0x80000000u) ? ~u : (u | 0x80000000u); // order-preserving
    int n = r & (N_DIM - 1);
    unsigned long long key = ((unsigned long long)ou << 15) | (unsigned)(n ^ (N_DIM - 1));

    keys[r]   = key;
    labels[r] = (unsigned char)cidx;
    atomicAdd(&hist[(unsigned)(r >> 15) * HBINS + (unsigned)(key >> 35)], 1u);
}

// ---------------------------------------------------------------------------
// Kernel 2 (fused): exact top-1024 via histogram threshold + boundary-bin sort,
// full bitonic sort of the 1024, class-sparse mask NMS, output. 1 block/batch.
// ---------------------------------------------------------------------------
__global__ __launch_bounds__(1024) void selnms_kernel(const float* __restrict__ pred,
                                                      const unsigned long long* __restrict__ keys,
                                                      const unsigned char* __restrict__ labels,
                                                      const unsigned int* __restrict__ hist,
                                                      float* __restrict__ out) {
    const int b   = blockIdx.x;
    const int tid = threadIdx.x;
    const int wid = tid >> 6;
    const int lane = tid & 63;

    __shared__ unsigned long long sel[TOPK_K];        // 8 KB
    alignas(16) __shared__ char scratch[32768];       // 32 KB, phase-reused
    __shared__ unsigned long long keepm_s[16];
    __shared__ unsigned int binT_s, selcnt_s, bincnt_s;

    unsigned int* hist_s = (unsigned int*)scratch;                 // phase 1: 16 KB
    unsigned long long* binlist = (unsigned long long*)scratch;    // phase 2: 32 KB (cap 4096)
    float* sx1 = (float*)scratch;                                  // phase 3 (NMS): 20 KB + 1 KB
    float* sy1 = (float*)(scratch + 4096);
    float* sx2 = (float*)(scratch + 8192);
    float* sy2 = (float*)(scratch + 12288);
    float* sarea = (float*)(scratch + 16384);
    unsigned long long* plab = (unsigned long long*)(scratch + 20480); // 128 u64 packed labels

    if (tid == 0) { selcnt_s = 0u; bincnt_s = 0u; }
    for (int i = tid; i < HBINS; i += 1024) hist_s[i] = hist[b * HBINS + i];
    __syncthreads();

    // ---- find threshold bin (wave 0) ----
    if (wid == 0) {
        unsigned partial = 0;
        const int b0 = lane * 64;
        for (int k = 0; k < 64; ++k) partial += hist_s[b0 + k];
        unsigned v = partial;
        for (int off = 1; off < 64; off <<= 1) {     // suffix-inclusive sum over lanes
            unsigned u2 = __shfl_down(v, off);
            if (lane + off < 64) v += u2;
        }
        unsigned above = v - partial;                // strictly-higher lanes' bins
        if (above < TOPK_K && above + partial >= TOPK_K) {
            unsigned cum = above;
            for (int bin = b0 + 63; ; --bin) {
                cum += hist_s[bin];
                if (cum >= TOPK_K) { binT_s = (unsigned)bin; break; }
            }
        }
    }
    __syncthreads();
    const unsigned binT = binT_s;
    __syncthreads();   // hist_s dead; scratch becomes binlist

    // ---- single compacting pass over keys ----
    const unsigned long long* K = keys + (size_t)b * N_DIM;
    for (int n = tid; n < N_DIM; n += 1024) {
        unsigned long long k = K[n];
        unsigned bin = (unsigned)(k >> 35);
        if (bin > binT) {
            unsigned p = atomicAdd(&selcnt_s, 1u);
            sel[p] = k;
        } else if (bin == binT) {
            unsigned p = atomicAdd(&bincnt_s, 1u);
            if (p < 4096u) binlist[p] = k;
        }
    }
    __syncthreads();
    const unsigned C1 = selcnt_s;
    const unsigned R  = TOPK_K - C1;       // how many to take from boundary bin
    unsigned bincnt = bincnt_s;
    if (bincnt > 4096u) bincnt = 4096u;    // never triggered (safety clamp)

    // ---- sort boundary bin DESCENDING (bitonic, padded to pow2) ----
    unsigned P = 1; while (P < bincnt) P <<= 1;
    for (unsigned i = bincnt + tid; i < P; i += 1024) binlist[i] = 0ull;
    __syncthreads();
    for (unsigned kk = 2; kk <= P; kk <<= 1) {
        for (unsigned jj = kk >> 1; jj > 0; jj >>= 1) {
            for (unsigned t = tid; t < P; t += 1024) {
                unsigned ixj = t ^ jj;
                if (ixj > t) {
                    unsigned long long a = binlist[t], c2 = binlist[ixj];
                    bool up = ((t & kk) == 0);
                    if ((a < c2) == up) { binlist[t] = c2; binlist[ixj] = a; }
                }
            }
            __syncthreads();
        }
    }
    if ((unsigned)tid < R) sel[C1 + tid] = binlist[tid];
    __syncthreads();

    // ---- sort the exact top-1024 ASCENDING (read reversed below) ----
    for (unsigned kk = 2; kk <= TOPK_K; kk <<= 1) {
        for (unsigned jj = kk >> 1; jj > 0; jj >>= 1) {
            unsigned t = tid, ixj = t ^ jj;
            if (ixj > t) {
                unsigned long long a = sel[t], c2 = sel[ixj];
                bool up = ((t & kk) == 0);
                if ((a > c2) == up) { sel[t] = c2; sel[ixj] = a; }
            }
            __syncthreads();
        }
    }

    // ---- decode rank-j box ----
    const int j = tid;
    unsigned long long key = sel[(TOPK_K - 1) - j];
    int n = (N_DIM - 1) - (int)(key & (unsigned long long)(N_DIM - 1));
    unsigned int ou = (unsigned int)(key >> 15);
    unsigned int ob = (ou & 0x80000000u) ? (ou & 0x7FFFFFFFu) : ~ou;
    float score = __uint_as_float(ob);
    bool validk = (score >= 0.0f);
    int lab = (int)labels[(size_t)b * N_DIM + n];

    const float* row = pred + ((size_t)b * N_DIM + n) * ROW_F;
    float cx = row[0], cy = row[1], w = row[2], h = row[3];
    float x1 = cx - w * 0.5f, y1 = cy - h * 0.5f;
    float x2 = w + x1,        y2 = h + y1;          // reference: xy2 = wh + xy1
    float off = (float)lab * OFFSET_F;
    float nx1 = x1 + off, ny1 = y1 + off, nx2 = x2 + off, ny2 = y2 + off;
    float area = (nx2 - nx1) * (ny2 - ny1);
    __syncthreads();   // scratch becomes NMS arrays

    sx1[j] = nx1; sy1[j] = ny1; sx2[j] = nx2; sy2[j] = ny2; sarea[j] = area;
    ((unsigned char*)plab)[j] = (unsigned char)lab;
    __syncthreads();

    // ---- build this thread's suppression-mask column (same-class only) ----
    // Cross-class IoU is exactly 0: class offset 241 >= y-extent bound (231),
    // so ih==0 (adjacent) or no overlap at all => inter==0 => iou==0 < 0.65.
    unsigned long long mask[16];
    const unsigned long long rep = (unsigned long long)(unsigned char)lab * 0x0101010101010101ull;
    const unsigned long long M7F = 0x7F7F7F7F7F7F7F7Full;
#pragma unroll
    for (int c = 0; c < 16; ++c) {
        unsigned long long m = 0ull;
#pragma unroll
        for (int w8 = 0; w8 < 8; ++w8) {
            const int wi = c * 8 + w8;
            unsigned long long x = plab[wi] ^ rep;
            // exact per-byte zero detect (no cross-byte carries)
            unsigned long long zm = ~(((x & M7F) + M7F) | x | M7F);
            while (zm) {
                int bit = __builtin_ctzll(zm); zm &= zm - 1ull;
                int i = wi * 8 + (bit >> 3);
                float ix1 = fmaxf(sx1[i], nx1), iy1 = fmaxf(sy1[i], ny1);
                float ix2 = fminf(sx2[i], nx2), iy2 = fminf(sy2[i], ny2);
                float iw = fmaxf(ix2 - ix1, 0.0f), ih = fmaxf(iy2 - iy1, 0.0f);
                float inter = iw * ih;
                float iou = inter / (sarea[i] + area - inter + 1e-12f);
                if (iou > NMS_THRE_F) m |= 1ull << (i & 63);
            }
        }
        mask[c] = m;
    }

    // ---- chunked greedy scan: 16 x (64-iter ballot loop on one wave) ----
    bool supp = false;
    bool keepb = false;
#pragma unroll
    for (int c = 0; c < 16; ++c) {
        if (wid == c) {
            unsigned long long W = mask[c];
            unsigned long long vm = __ballot(validk && !supp);
            unsigned long long suppm = 0ull, km = 0ull;
            for (int i = 0; i < 64; ++i) {
                unsigned long long bits = __ballot(((W >> i) & 1ull) != 0ull);
                bool can = ((vm >> i) & 1ull) && !((suppm >> i) & 1ull);
                if (can) { km |= 1ull << i; suppm |= bits; }
            }
            keepb = ((km >> lane) & 1ull) != 0ull;
            if (lane == 0) keepm_s[c] = km;
        }
        __syncthreads();
        if (wid > c) {
            if (mask[c] & keepm_s[c]) supp = true;
        }
    }

    float keepf = keepb ? 1.0f : 0.0f;
    float* o = out + ((size_t)b * TOPK_K + j) * 6;
    o[0] = x1 * keepf;
    o[1] = y1 * keepf;
    o[2] = x2 * keepf;
    o[3] = y2 * keepf;
    o[4] = score * keepf;
    o[5] = (float)lab * keepf;
}

// ---------------------------------------------------------------------------
extern "C" void kernel_launch(void* const* d_in, const int* in_sizes, int n_in,
                              void* d_out, int out_size, void* d_ws, size_t ws_size,
                              hipStream_t stream) {
    const float* pred = (const float*)d_in[0];
    float* out = (float*)d_out;

    // workspace layout
    unsigned long long* keys   = (unsigned long long*)d_ws;                        // 2 MB
    unsigned char*      labels = (unsigned char*)((char*)d_ws + (2u << 20));       // 256 KB
    unsigned int*       hist   = (unsigned int*)((char*)d_ws + (2u << 20) + (512u << 10)); // 128 KB

    hipMemsetAsync(hist, 0, B_DIM * HBINS * sizeof(unsigned int), stream);
    decode_kernel<<<(B_DIM * N_DIM) / 256, 256, 0, stream>>>(pred, keys, labels, hist);
    selnms_kernel<<<B_DIM, 1024, 0, stream>>>(pred, keys, labels, hist, out);
}

// Round 3
// 111.965 us; speedup vs baseline: 5.2730x; 3.1540x over previous
//
#include <hip/hip_runtime.h>
#include <hip/hip_bf16.h>

// Keep every fp op matching numpy/jax f32 op-by-op rounding (no fma fusion):
#pragma clang fp contract(off)

#define NUM_CLASSES 100
#define B_DIM 8
#define N_DIM 32768
#define TOPK_K 1024
#define ROW_F 105
#define CONF_THRE_F 0.001f
#define NMS_THRE_F 0.65f
#define OFFSET_F 241.0f   // MAX_DIM + 1

typedef unsigned long long u64;
typedef unsigned int u32;

__device__ __forceinline__ u64 shfl_xor64(u64 v, int mask) {
    int lo = __shfl_xor((int)(v & 0xFFFFFFFFull), mask);
    int hi = __shfl_xor((int)(v >> 32), mask);
    return ((u64)(u32)hi << 32) | (u32)lo;
}
__device__ __forceinline__ u64 shfl64(u64 v, int src) {
    int lo = __shfl((int)(v & 0xFFFFFFFFull), src);
    int hi = __shfl((int)(v >> 32), src);
    return ((u64)(u32)hi << 32) | (u32)lo;
}

// key layout (54 bits): [ou(32) << 22] | [(32767-n)(15) << 7] | label(7)
__device__ __forceinline__ u32 key_bin1(u64 k) {   // ou bits 30..18, 0 if invalid
    return ((k >> 53) & 1ull) ? (u32)((k >> 40) & 0x1FFFull) : 0u;
}
__device__ __forceinline__ u32 key_bin2(u64 k) {   // ou bits 17..5
    return (u32)((k >> 27) & 0x1FFFull);
}

// ---------------------------------------------------------------------------
// Kernel 1: one wave per row. Coalesced loads, shfl-xor argmax, packed key.
// ---------------------------------------------------------------------------
__global__ __launch_bounds__(256) void decode_kernel(const float* __restrict__ pred,
                                                     u64* __restrict__ keys) {
    const int lane = threadIdx.x & 63;
    const int wid  = threadIdx.x >> 6;
    const int r    = (blockIdx.x << 2) + wid;          // 65536 blocks * 4 rows

    const float* row = pred + (size_t)r * ROW_F;
    float f0 = row[lane];                              // positions 0..63
    float f1 = (lane < 41) ? row[64 + lane] : -1.0f;   // positions 64..104

    float obj = __shfl(f0, 4);

    // candidate keys: (orderbits(f) << 7) | (99 - class); all class scores >= 0
    u32 b0 = __float_as_uint(f0) | 0x80000000u;
    u32 b1 = __float_as_uint(f1) | 0x80000000u;
    u64 k0 = (lane >= 5) ? (((u64)b0 << 7) | (u64)(99 - (lane - 5))) : 0ull;
    u64 k1 = (lane < 41) ? (((u64)b1 << 7) | (u64)(99 - (lane + 59))) : 0ull;
    u64 kk = (k1 > k0) ? k1 : k0;
#pragma unroll
    for (int off = 32; off; off >>= 1) {
        u64 o = shfl_xor64(kk, off);
        if (o > kk) kk = o;
    }

    float cmax = __uint_as_float((u32)(kk >> 7) & 0x7FFFFFFFu);
    int   cls  = 99 - (int)(kk & 0x7Full);

    float score = obj * cmax;                    // same op order as reference
    bool  valid = (score * cmax) >= CONF_THRE_F;
    float mval  = valid ? score : -1.0f;

    u32 u  = __float_as_uint(mval);
    u32 ou = (u & 0x80000000u) ? ~u : (u | 0x80000000u);   // order-preserving

    u64 key = ((u64)ou << 22) |
              ((u64)(u32)((r & (N_DIM - 1)) ^ (N_DIM - 1)) << 7) |
              (u64)cls;
    if (lane == 0) keys[r] = key;
}

// wave-0 suffix scan over an 8192-bin LDS histogram: find bin with
// count(bin > binT) < target <= count(bin >= binT); optionally report C1.
__device__ __forceinline__ void scan_hist(const u32* h, u32 target,
                                          u32* binT_out, u32* c1_out) {
    const int lane = threadIdx.x & 63;
    u32 partial = 0;
    for (int k = 0; k < 128; ++k) partial += h[lane * 128 + k];
    u32 v = partial;
#pragma unroll
    for (int off = 1; off < 64; off <<= 1) {
        u32 o = __shfl_down(v, off);
        if (lane + off < 64) v += o;
    }
    u32 above = v - partial;                 // bins in strictly-higher lanes
    if (above < target && above + partial >= target) {
        u32 cum = above;
        int bin = lane * 128 + 127;
        for (;; --bin) {
            cum += h[bin];
            if (cum >= target) break;
        }
        *binT_out = (u32)bin;
        if (c1_out) *c1_out = cum - h[bin];  // strictly above binT
    }
}

// ---------------------------------------------------------------------------
// Kernel 2 (fused): two-level histogram select -> enumeration rank (sorted
// top-1024) -> class-sparse mask NMS -> output. One 1024-thread block/batch.
// ---------------------------------------------------------------------------
__global__ __launch_bounds__(1024) void selnms_kernel(const float* __restrict__ pred,
                                                      const u64* __restrict__ keys,
                                                      float* __restrict__ out) {
    const int b    = blockIdx.x;
    const int tid  = threadIdx.x;
    const int wid  = tid >> 6;
    const int lane = tid & 63;

    __shared__ u64 sel[TOPK_K];                    // 8 KB, rank-ordered keys
    alignas(16) __shared__ char SC[32768];         // phase-reused region
    __shared__ u64 keepm_s[16];
    __shared__ u32 binT_s, binT2_s, C1_s, cnt_s;
    __shared__ u32 cls_cnt[104], cls_start[104], cls_fill[104];

    u32* hist = (u32*)SC;                          // phase A/B: 8192 bins
    u64* cand = (u64*)SC;                          // phase C:   2048 keys max
    float* sx1 = (float*)SC;                       // phase D (NMS):
    float* sy1 = (float*)(SC + 4096);
    float* sx2 = (float*)(SC + 8192);
    float* sy2 = (float*)(SC + 12288);
    float* sar = (float*)(SC + 16384);
    unsigned short* items = (unsigned short*)(SC + 20480);

    const u64* K = keys + (size_t)b * N_DIM;

    // ---- init ----
    if (tid < 100) { cls_cnt[tid] = 0u; cls_fill[tid] = 0u; }
    if (tid == 0) cnt_s = 0u;
    for (int i = tid; i < 8192; i += 1024) hist[i] = 0u;
    __syncthreads();

    // ---- level-1 histogram ----
    for (int n = tid; n < N_DIM; n += 1024)
        atomicAdd(&hist[key_bin1(K[n])], 1u);
    __syncthreads();
    if (wid == 0) scan_hist(hist, TOPK_K, &binT_s, &C1_s);
    __syncthreads();
    const u32 binT = binT_s;
    const u32 C1   = C1_s;
    __syncthreads();

    // ---- level-2 histogram (keys in binT only) ----
    for (int i = tid; i < 8192; i += 1024) hist[i] = 0u;
    __syncthreads();
    for (int n = tid; n < N_DIM; n += 1024) {
        u64 k = K[n];
        if (key_bin1(k) == binT) atomicAdd(&hist[key_bin2(k)], 1u);
    }
    __syncthreads();
    if (wid == 0) scan_hist(hist, TOPK_K - C1, &binT2_s, nullptr);
    __syncthreads();
    const u32 binT2 = binT2_s;
    __syncthreads();                               // hist dead -> cand region

    // ---- compact candidates: (bin1 > binT) or (bin1==binT && bin2>=binT2) ----
    for (int n = tid; n < N_DIM; n += 1024) {
        u64 k = K[n];
        u32 b1 = key_bin1(k);
        if (b1 > binT || (b1 == binT && key_bin2(k) >= binT2)) {
            u32 p = atomicAdd(&cnt_s, 1u);
            if (p < 2048u) cand[p] = k;
        }
    }
    __syncthreads();
    int C = (int)cnt_s; if (C > 2048) C = 2048;    // C in [1024, ~1030] typ.
    if (tid == 0 && (C & 1)) cand[C] = 0ull;       // pad to even
    const int CP = (C + 1) & ~1;
    __syncthreads();

    // ---- enumeration rank (keys unique -> ranks unique) ----
    u64 my0 = (tid < C) ? cand[tid] : 0ull;
    bool h1 = (tid + 1024) < C;
    u64 my1 = h1 ? cand[tid + 1024] : 0ull;
    u32 r0 = 0, r1 = 0;
    if (!h1) {
        for (int i = 0; i < CP; i += 2) {
            ulonglong2 kk2 = *(const ulonglong2*)(cand + i);
            r0 += (kk2.x > my0) + (kk2.y > my0);
        }
    } else {
        for (int i = 0; i < CP; i += 2) {
            ulonglong2 kk2 = *(const ulonglong2*)(cand + i);
            r0 += (kk2.x > my0) + (kk2.y > my0);
            r1 += (kk2.x > my1) + (kk2.y > my1);
        }
    }
    if (tid < C && r0 < TOPK_K) sel[r0] = my0;     // rank 0 = largest
    if (h1 && r1 < TOPK_K) sel[r1] = my1;
    __syncthreads();                               // cand dead -> NMS arrays

    // ---- decode rank-tid box ----
    u64 key = sel[tid];
    int lab = (int)(key & 0x7Full);
    int n   = (N_DIM - 1) - (int)((key >> 7) & (u64)(N_DIM - 1));
    u32 ou  = (u32)(key >> 22);
    u32 ob  = (ou & 0x80000000u) ? (ou & 0x7FFFFFFFu) : ~ou;
    float score = __uint_as_float(ob);
    bool validk = (score >= 0.0f);

    const float* row = pred + ((size_t)b * N_DIM + n) * ROW_F;
    float cx = row[0], cy = row[1], w = row[2], h = row[3];
    float x1 = cx - w * 0.5f, y1 = cy - h * 0.5f;
    float x2 = w + x1,        y2 = h + y1;         // reference: xy2 = wh + xy1
    float off = (float)lab * OFFSET_F;
    float nx1 = x1 + off, ny1 = y1 + off, nx2 = x2 + off, ny2 = y2 + off;
    float area = (nx2 - nx1) * (ny2 - ny1);

    sx1[tid] = nx1; sy1[tid] = ny1; sx2[tid] = nx2; sy2[tid] = ny2; sar[tid] = area;
    atomicAdd(&cls_cnt[lab], 1u);
    __syncthreads();
    if (tid == 0) {
        u32 s = 0;
        for (int c = 0; c < 100; ++c) { cls_start[c] = s; s += cls_cnt[c]; }
    }
    __syncthreads();
    {
        u32 p = cls_start[lab] + atomicAdd(&cls_fill[lab], 1u);
        items[p] = (unsigned short)tid;
    }
    __syncthreads();

    // ---- suppression-mask column, same-class partners only (~10 IoUs) ----
    u64 m0=0,m1=0,m2=0,m3=0,m4=0,m5=0,m6=0,m7=0,
        m8=0,m9=0,m10=0,m11=0,m12=0,m13=0,m14=0,m15=0;
    {
        const int s0 = (int)cls_start[lab];
        const int e0 = s0 + (int)cls_cnt[lab];
        for (int p = s0; p < e0; ++p) {
            int i = (int)items[p];
            if (i == tid) continue;
            float ix1 = fmaxf(sx1[i], nx1), iy1 = fmaxf(sy1[i], ny1);
            float ix2 = fminf(sx2[i], nx2), iy2 = fminf(sy2[i], ny2);
            float iw = fmaxf(ix2 - ix1, 0.0f), ih = fmaxf(iy2 - iy1, 0.0f);
            float inter = iw * ih;
            float iou = inter / (sar[i] + area - inter + 1e-12f);
            if (iou > NMS_THRE_F) {
                u64 bit = 1ull << (i & 63);
                int ch = i >> 6;
                m0  |= (ch == 0)  ? bit : 0ull;  m1  |= (ch == 1)  ? bit : 0ull;
                m2  |= (ch == 2)  ? bit : 0ull;  m3  |= (ch == 3)  ? bit : 0ull;
                m4  |= (ch == 4)  ? bit : 0ull;  m5  |= (ch == 5)  ? bit : 0ull;
                m6  |= (ch == 6)  ? bit : 0ull;  m7  |= (ch == 7)  ? bit : 0ull;
                m8  |= (ch == 8)  ? bit : 0ull;  m9  |= (ch == 9)  ? bit : 0ull;
                m10 |= (ch == 10) ? bit : 0ull;  m11 |= (ch == 11) ? bit : 0ull;
                m12 |= (ch == 12) ? bit : 0ull;  m13 |= (ch == 13) ? bit : 0ull;
                m14 |= (ch == 14) ? bit : 0ull;  m15 |= (ch == 15) ? bit : 0ull;
            }
        }
    }

    // ---- greedy scan, 16 chunks; serial work only on conflicted lanes ----
    bool supp = false, keepb = false;
#define CHUNK_STEP(c, mc)                                                     \
    {                                                                         \
        if (wid == (c)) {                                                     \
            u64 W  = (mc);                                                    \
            u64 vm = __ballot(validk && !supp);                               \
            u64 S  = __ballot(W != 0ull);                                     \
            u64 km = vm & ~S;                                                 \
            u64 suppm = 0ull, mm = S;                                         \
            while (mm) {                                                      \
                int i = __builtin_ctzll(mm); mm &= mm - 1ull;                 \
                u64 Wi = shfl64(W, i);                                        \
                if (((vm >> i) & 1ull) && !((suppm >> i) & 1ull)) {           \
                    km |= 1ull << i; suppm |= Wi;                             \
                }                                                             \
            }                                                                 \
            keepb = ((km >> lane) & 1ull) != 0ull;                            \
            if (lane == 0) keepm_s[(c)] = km;                                 \
        }                                                                     \
        __syncthreads();                                                      \
        if (wid > (c) && ((mc) & keepm_s[(c)])) supp = true;                  \
    }
    CHUNK_STEP(0, m0)   CHUNK_STEP(1, m1)   CHUNK_STEP(2, m2)   CHUNK_STEP(3, m3)
    CHUNK_STEP(4, m4)   CHUNK_STEP(5, m5)   CHUNK_STEP(6, m6)   CHUNK_STEP(7, m7)
    CHUNK_STEP(8, m8)   CHUNK_STEP(9, m9)   CHUNK_STEP(10, m10) CHUNK_STEP(11, m11)
    CHUNK_STEP(12, m12) CHUNK_STEP(13, m13) CHUNK_STEP(14, m14) CHUNK_STEP(15, m15)
#undef CHUNK_STEP

    float keepf = keepb ? 1.0f : 0.0f;
    float* o = out + ((size_t)b * TOPK_K + tid) * 6;
    o[0] = x1 * keepf;
    o[1] = y1 * keepf;
    o[2] = x2 * keepf;
    o[3] = y2 * keepf;
    o[4] = score * keepf;
    o[5] = (float)lab * keepf;
}

// ---------------------------------------------------------------------------
extern "C" void kernel_launch(void* const* d_in, const int* in_sizes, int n_in,
                              void* d_out, int out_size, void* d_ws, size_t ws_size,
                              hipStream_t stream) {
    const float* pred = (const float*)d_in[0];
    float* out = (float*)d_out;

    u64* keys = (u64*)d_ws;   // 2 MB

    decode_kernel<<<(B_DIM * N_DIM) / 4, 256, 0, stream>>>(pred, keys);
    selnms_kernel<<<B_DIM, 1024, 0, stream>>>(pred, keys, out);
}